// Round 11
// baseline (1608.171 us; speedup 1.0000x reference)
//
#include <hip/hip_runtime.h>
#include <cstddef>

#define NN 3072
#define RR 16
#define NB 16

typedef float f32x4 __attribute__((ext_vector_type(4)));

// Prologue: key[i] = valid ? batch[i] : -1, plus batch row boundaries
// start[b] = first row index with batch >= b (batch is sorted). start[NB]=NN.
__global__ void frd_prep_kernel(const int* __restrict__ cls,
                                const int* __restrict__ batch,
                                int* __restrict__ key,
                                int* __restrict__ start) {
    int t = blockIdx.x * blockDim.x + threadIdx.x;
    if (t < NN) {
        int c = cls[t];
        int b = batch[t];
        key[t] = (c != 24 && c != 25 && c != 26) ? b : -1;
        int prev = (t == 0) ? -1 : batch[t - 1];
        for (int bb = prev + 1; bb <= b; ++bb) start[bb] = t;
        if (t == NN - 1)
            for (int bb = b + 1; bb <= NB; ++bb) start[bb] = NN;
    }
}

// K1: default-writer. Thread owns 4 consecutive pairs (256 B contiguous).
// Store VALUES are compile-time constants; the only data dependence is the
// per-pair skip mask from L1-resident key loads (1 wave-uniform + 1 int4).
// Skips exactly the pairs K2 writes: ki>=0 && kj==ki.
__global__ __launch_bounds__(256)
void frd_fill_kernel(const int* __restrict__ key, float* __restrict__ out) {
    const int t = blockIdx.x * 256 + threadIdx.x;      // [0, NN*NN/4)
    const int pair0 = t * 4;
    const int i = pair0 / NN;                           // magic-mul
    const int j0 = pair0 - i * NN;                      // NN%4==0 -> same row
    const int ki = key[i];
    const int4 kj = *reinterpret_cast<const int4*>(key + j0);
    float* op = out + (size_t)pair0 * RR;
    const f32x4 d1 = {1.0f, 0.0f, 0.0f, 0.0f};          // one_hot(0,R) head
    const f32x4 dz = {0.0f, 0.0f, 0.0f, 0.0f};

    if (!(ki >= 0 && kj.x == ki)) {
        __builtin_nontemporal_store(d1, reinterpret_cast<f32x4*>(op + 0));
        __builtin_nontemporal_store(dz, reinterpret_cast<f32x4*>(op + 4));
        __builtin_nontemporal_store(dz, reinterpret_cast<f32x4*>(op + 8));
        __builtin_nontemporal_store(dz, reinterpret_cast<f32x4*>(op + 12));
    }
    if (!(ki >= 0 && kj.y == ki)) {
        __builtin_nontemporal_store(d1, reinterpret_cast<f32x4*>(op + 16));
        __builtin_nontemporal_store(dz, reinterpret_cast<f32x4*>(op + 20));
        __builtin_nontemporal_store(dz, reinterpret_cast<f32x4*>(op + 24));
        __builtin_nontemporal_store(dz, reinterpret_cast<f32x4*>(op + 28));
    }
    if (!(ki >= 0 && kj.z == ki)) {
        __builtin_nontemporal_store(d1, reinterpret_cast<f32x4*>(op + 32));
        __builtin_nontemporal_store(dz, reinterpret_cast<f32x4*>(op + 36));
        __builtin_nontemporal_store(dz, reinterpret_cast<f32x4*>(op + 40));
        __builtin_nontemporal_store(dz, reinterpret_cast<f32x4*>(op + 44));
    }
    if (!(ki >= 0 && kj.w == ki)) {
        __builtin_nontemporal_store(d1, reinterpret_cast<f32x4*>(op + 48));
        __builtin_nontemporal_store(dz, reinterpret_cast<f32x4*>(op + 52));
        __builtin_nontemporal_store(dz, reinterpret_cast<f32x4*>(op + 56));
        __builtin_nontemporal_store(dz, reinterpret_cast<f32x4*>(op + 60));
    }
}

// K2: diagonal-rectangle writer. One block per row i; exits if key invalid.
// Threads sweep j over row i's batch column range, writing the key-match
// pairs: product if seg==0 (off-diagonal), else the default.
__global__ __launch_bounds__(256)
void frd_diag_kernel(const float* __restrict__ z1,
                     const float* __restrict__ z2,
                     const float* __restrict__ seg,
                     const int* __restrict__ key,
                     const int* __restrict__ start,
                     float* __restrict__ out) {
    const int i = blockIdx.x;
    const int ki = key[i];
    if (ki < 0) return;
    const int s0 = start[ki];
    const int s1 = start[ki + 1];
    const float4 a0 = *reinterpret_cast<const float4*>(z1 + i * RR + 0);
    const float4 a1 = *reinterpret_cast<const float4*>(z1 + i * RR + 4);
    const float4 a2 = *reinterpret_cast<const float4*>(z1 + i * RR + 8);
    const float4 a3 = *reinterpret_cast<const float4*>(z1 + i * RR + 12);
    const f32x4 d1 = {1.0f, 0.0f, 0.0f, 0.0f};
    const f32x4 dz = {0.0f, 0.0f, 0.0f, 0.0f};

    for (int j = s0 + threadIdx.x; j < s1; j += 256) {
        if (key[j] != ki) continue;                     // K1 wrote this pair
        const float s = seg[i * NN + j];
        const float seg_eff = s + ((i == j) ? 1.0f : 0.0f);
        float* op = out + ((size_t)i * NN + j) * RR;
        if (seg_eff == 0.0f) {
            const float4 b0 = *reinterpret_cast<const float4*>(z2 + j * RR + 0);
            const float4 b1 = *reinterpret_cast<const float4*>(z2 + j * RR + 4);
            const float4 b2 = *reinterpret_cast<const float4*>(z2 + j * RR + 8);
            const float4 b3 = *reinterpret_cast<const float4*>(z2 + j * RR + 12);
            f32x4 r0 = {a0.x * b0.x, a0.y * b0.y, a0.z * b0.z, a0.w * b0.w};
            f32x4 r1 = {a1.x * b1.x, a1.y * b1.y, a1.z * b1.z, a1.w * b1.w};
            f32x4 r2 = {a2.x * b2.x, a2.y * b2.y, a2.z * b2.z, a2.w * b2.w};
            f32x4 r3 = {a3.x * b3.x, a3.y * b3.y, a3.z * b3.z, a3.w * b3.w};
            __builtin_nontemporal_store(r0, reinterpret_cast<f32x4*>(op + 0));
            __builtin_nontemporal_store(r1, reinterpret_cast<f32x4*>(op + 4));
            __builtin_nontemporal_store(r2, reinterpret_cast<f32x4*>(op + 8));
            __builtin_nontemporal_store(r3, reinterpret_cast<f32x4*>(op + 12));
        } else {
            __builtin_nontemporal_store(d1, reinterpret_cast<f32x4*>(op + 0));
            __builtin_nontemporal_store(dz, reinterpret_cast<f32x4*>(op + 4));
            __builtin_nontemporal_store(dz, reinterpret_cast<f32x4*>(op + 8));
            __builtin_nontemporal_store(dz, reinterpret_cast<f32x4*>(op + 12));
        }
    }
}

extern "C" void kernel_launch(void* const* d_in, const int* in_sizes, int n_in,
                              void* d_out, int out_size, void* d_ws, size_t ws_size,
                              hipStream_t stream) {
    const float* z1  = (const float*)d_in[0];
    const float* z2  = (const float*)d_in[1];
    const float* seg = (const float*)d_in[2];
    const int* cls   = (const int*)d_in[3];
    const int* batch = (const int*)d_in[4];
    float* out = (float*)d_out;
    int* key   = (int*)d_ws;
    int* start = key + NN;

    frd_prep_kernel<<<(NN + 255) / 256, 256, 0, stream>>>(cls, batch, key, start);
    frd_fill_kernel<<<NN * NN / 4 / 256, 256, 0, stream>>>(key, out);
    frd_diag_kernel<<<NN, 256, 0, stream>>>(z1, z2, seg, key, start, out);
}

// Round 12
// 126.722 us; speedup vs baseline: 12.6905x; 12.6905x over previous
//
#include <hip/hip_runtime.h>
#include <cstddef>

#define NN 3072
#define RR 16
#define NB 16
#define UNROLL 8

typedef float f32x4 __attribute__((ext_vector_type(4)));

// Prologue: key[i] = valid ? batch[i] : -1, plus batch row boundaries
// start[b] = first row with batch >= b (batch sorted). start[NB]=NN.
__global__ void frd_prep_kernel(const int* __restrict__ cls,
                                const int* __restrict__ batch,
                                int* __restrict__ key,
                                int* __restrict__ start) {
    int t = blockIdx.x * blockDim.x + threadIdx.x;
    if (t < NN) {
        int c = cls[t];
        int b = batch[t];
        key[t] = (c != 24 && c != 25 && c != 26) ? b : -1;
        int prev = (t == 0) ? -1 : batch[t - 1];
        for (int bb = prev + 1; bb <= b; ++bb) start[bb] = t;
        if (t == NN - 1)
            for (int bb = b + 1; bb <= NB; ++bb) start[bb] = NN;
    }
}

// K1: default-writer, R8 winning mapping (idx = bid*2048 + k*256 + tid ->
// every store instruction is a contiguous 1 KB wave burst; lanes 4c..4c+3
// cover pair c, one 64 B line). Store VALUES are constants; mask depends only
// on L1-resident key[] loads. Skipped pairs drop whole 64 B lines (no RMW).
__global__ __launch_bounds__(256)
void frd_fill_kernel(const int* __restrict__ key, float* __restrict__ out) {
    const int base = blockIdx.x * (256 * UNROLL) + threadIdx.x;
    const int q = threadIdx.x & 3;
    const f32x4 val = {(q == 0) ? 1.0f : 0.0f, 0.0f, 0.0f, 0.0f};

#pragma unroll
    for (int k = 0; k < UNROLL; ++k) {
        const int idx = base + k * 256;
        const int pair = idx >> 2;
        const int i = pair / NN;          // magic-mul
        const int j = pair - i * NN;
        const int ki = key[i];            // L1-resident (12 KB)
        const int kj = key[j];
        const bool skip = (ki >= 0) && (ki == kj);   // K2 writes these
        if (!skip)
            __builtin_nontemporal_store(val, reinterpret_cast<f32x4*>(out + (size_t)idx * 4));
    }
}

// K2: diagonal-rectangle writer. One block per row i (exit if key invalid).
// 4 lanes per pair (lane q writes quad q) -> full-line coalesced stores.
// Sweeps j over row i's batch range; writes product if seg==0 else default.
__global__ __launch_bounds__(256)
void frd_diag_kernel(const float* __restrict__ z1,
                     const float* __restrict__ z2,
                     const float* __restrict__ seg,
                     const int* __restrict__ key,
                     const int* __restrict__ start,
                     float* __restrict__ out) {
    const int i = blockIdx.x;
    const int ki = key[i];
    if (ki < 0) return;
    const int s0 = start[ki];
    const int s1 = start[ki + 1];
    const int q = threadIdx.x & 3;
    const int g = threadIdx.x >> 2;       // pair group [0,64)

    const float4 a = *reinterpret_cast<const float4*>(z1 + i * RR + q * 4);
    const float d0 = (q == 0) ? 1.0f : 0.0f;

    for (int j = s0 + g; j < s1; j += 64) {
        if (key[j] != ki) continue;                   // K1 wrote this pair
        const float s = seg[i * NN + j];              // 4-lane broadcast
        const float seg_eff = s + ((i == j) ? 1.0f : 0.0f);
        float* op = out + ((size_t)i * NN + j) * RR + q * 4;
        f32x4 r;
        if (seg_eff == 0.0f) {
            const float4 b = *reinterpret_cast<const float4*>(z2 + j * RR + q * 4);
            r.x = a.x * b.x; r.y = a.y * b.y; r.z = a.z * b.z; r.w = a.w * b.w;
        } else {
            r.x = d0; r.y = 0.0f; r.z = 0.0f; r.w = 0.0f;
        }
        __builtin_nontemporal_store(r, reinterpret_cast<f32x4*>(op));
    }
}

extern "C" void kernel_launch(void* const* d_in, const int* in_sizes, int n_in,
                              void* d_out, int out_size, void* d_ws, size_t ws_size,
                              hipStream_t stream) {
    const float* z1  = (const float*)d_in[0];
    const float* z2  = (const float*)d_in[1];
    const float* seg = (const float*)d_in[2];
    const int* cls   = (const int*)d_in[3];
    const int* batch = (const int*)d_in[4];
    float* out = (float*)d_out;
    int* key   = (int*)d_ws;
    int* start = key + NN;

    frd_prep_kernel<<<(NN + 255) / 256, 256, 0, stream>>>(cls, batch, key, start);
    const int total = NN * NN * 4;        // 37,748,736 = 18,432 * 256 * 8
    frd_fill_kernel<<<total / (256 * UNROLL), 256, 0, stream>>>(key, out);
    frd_diag_kernel<<<NN, 256, 0, stream>>>(z1, z2, seg, key, start, out);
}